// Round 3
// baseline (245.245 us; speedup 1.0000x reference)
//
#include <hip/hip_runtime.h>
#include <math.h>

// Problem constants (from reference)
#define B  2
#define S  2048
#define DM 1024
#define H  16
#define Dh 64
#define BH (B*H)

typedef short  bf16x8 __attribute__((ext_vector_type(8)));
typedef float  f32x4  __attribute__((ext_vector_type(4)));

__device__ __forceinline__ unsigned short f2bf(float f) {
    unsigned u = __float_as_uint(f);
    u = (u + 0x7fffu + ((u >> 16) & 1u)) >> 16;   // RNE, no NaN inputs here
    return (unsigned short)u;
}

// ---------------------------------------------------------------------------
// Kernel 0a: cast hidden_states + Wq|Wk|Wv (fp32) to bf16 workspace buffers.
// ---------------------------------------------------------------------------
__global__ __launch_bounds__(256) void cast_kernel(const float* __restrict__ X,
                                                   const float* __restrict__ Wq,
                                                   const float* __restrict__ Wk,
                                                   const float* __restrict__ Wv,
                                                   unsigned short* __restrict__ Xb,
                                                   unsigned short* __restrict__ Wb) {
    const long c = (long)(blockIdx.x * 256 + threadIdx.x) * 4;
    const float* src;
    unsigned short* dst;
    if (c < 4194304L) {
        src = X + c;  dst = Xb + c;
    } else {
        const long c2 = c - 4194304L;
        const int  wi = (int)(c2 >> 20);
        const long r  = c2 & 1048575L;
        src = (wi == 0 ? Wq : (wi == 1 ? Wk : Wv)) + r;
        dst = Wb + c2;
    }
    const float4 v = *(const float4*)src;
    ushort4 o;
    o.x = f2bf(v.x); o.y = f2bf(v.y); o.z = f2bf(v.z); o.w = f2bf(v.w);
    *(ushort4*)dst = o;
}

// ---------------------------------------------------------------------------
// Kernel 0b: RoPE cos/sin table: Tab[(b*S+s)*32 + i] = (cos, sin) of
//   pos[b,s] * 10000^(-i/32).  1 MB, L2-resident.
// ---------------------------------------------------------------------------
__global__ __launch_bounds__(256) void rope_tab_kernel(const int* __restrict__ pos,
                                                       float* __restrict__ Tab) {
    const int idx = blockIdx.x * 256 + threadIdx.x;   // < B*S*32 = 131072
    const int i  = idx & 31;
    const int bs = idx >> 5;
    const float p   = (float)pos[bs];
    const float inv = exp2f(-(float)i * 0.41524101186092029f);  // log2(1e4)/32
    float sn, cs;
    sincosf(p * inv, &sn, &cs);
    ((float2*)Tab)[idx] = make_float2(cs, sn);
}

// async global->LDS, 16B per lane
__device__ __forceinline__ void gload_lds16(const unsigned short* g, unsigned short* l) {
    __builtin_amdgcn_global_load_lds(
        (const __attribute__((address_space(1))) unsigned int*)g,
        (__attribute__((address_space(3))) unsigned int*)l,
        16, 0, 0);
}

// ---------------------------------------------------------------------------
// Kernel 1: fused QKV GEMM, bf16 MFMA. NEW: BK=64 as two BK=32 panels
//   (identical staging XOR-swizzle + frag-read per panel) -> 32 MFMAs per
//   barrier instead of 16, halving barrier/vmcnt-drain count. LDS 49.4 KB
//   still fits 3 blocks/CU (= grid's 768/256 anyway, so zero occupancy cost).
//   Epilogue: RoPE via table + LDS round-trip (Es, 2 halves) so ALL global
//   stores are coalesced 16B. V written transposed [B,H,Dh,S].
// ---------------------------------------------------------------------------
__global__ __launch_bounds__(256) void qkv_gemm(const unsigned short* __restrict__ Xb,
                                                const unsigned short* __restrict__ Wb,
                                                const float* __restrict__ Tab,
                                                unsigned short* __restrict__ Qb,
                                                unsigned short* __restrict__ Kb,
                                                unsigned short* __restrict__ Vb) {
    __shared__ __align__(16) unsigned short As[2][128 * 32];
    __shared__ __align__(16) unsigned short Bs[2][128 * 32];
    __shared__ __align__(16) unsigned short Es[64 * 136];   // epilogue staging

    const int tid  = threadIdx.x;
    const int w    = tid >> 6;
    const int lane = tid & 63;
    const int col  = lane & 15;
    const int quad = lane >> 4;
    const int m0 = blockIdx.x * 128;
    const int n0 = blockIdx.y * 128;
    const int mw = (w & 1) * 64;
    const int nw = (w >> 1) * 64;

    // staging: lane i loads row i>>2, global chunk (i&3)^(row&3)  (XOR swizzle)
    const int srow = lane >> 2;
    const int sk8  = (((lane & 3) ^ (srow & 3))) * 8;

    f32x4 acc[4][4] = {};

    for (int k0 = 0; k0 < 1024; k0 += 64) {
        __syncthreads();
        #pragma unroll
        for (int p = 0; p < 2; ++p) {
            #pragma unroll
            for (int it = 0; it < 2; ++it) {
                const int rbase = w * 16 + it * 64;
                gload_lds16(Xb + (size_t)(m0 + rbase + srow) * 1024 + k0 + p * 32 + sk8,
                            &As[p][rbase * 32]);
                gload_lds16(Wb + (size_t)(n0 + rbase + srow) * 1024 + k0 + p * 32 + sk8,
                            &Bs[p][rbase * 32]);
            }
        }
        __syncthreads();

        // global k-chunk quad lives at LDS slot quad^(row&3); row&3 == col&3
        const int fs = (quad ^ (col & 3)) * 8;
        #pragma unroll
        for (int p = 0; p < 2; ++p) {
            bf16x8 a[4], bb[4];
            #pragma unroll
            for (int i = 0; i < 4; ++i)
                a[i] = *(const bf16x8*)&As[p][(mw + i * 16 + col) * 32 + fs];
            #pragma unroll
            for (int j = 0; j < 4; ++j)
                bb[j] = *(const bf16x8*)&Bs[p][(nw + j * 16 + col) * 32 + fs];
            #pragma unroll
            for (int i = 0; i < 4; ++i)
                #pragma unroll
                for (int j = 0; j < 4; ++j)
                    acc[i][j] = __builtin_amdgcn_mfma_f32_16x16x32_bf16(a[i], bb[j], acc[i][j], 0, 0, 0);
        }
    }

    // ---- epilogue ----
    const int wsel = n0 >> 10;                 // 0=Q, 1=K, 2=V
    const int hh0  = (n0 & 1023) >> 6;         // base head of this n-tile
    const int bb2  = m0 >> 11;                 // batch (block never straddles)
    const int ssb  = m0 & 2047;                // seq base

    if (wsel == 2) {
        // V -> [B,H,Dh,S]; Es[dl][ssl] per dcol-half, b64 packed writes
        #pragma unroll
        for (int half = 0; half < 2; ++half) {
            __syncthreads();
            if ((w >> 1) == half) {            // waves whose nw == half*64
                #pragma unroll
                for (int i = 0; i < 4; ++i) {
                    const int sl = mw + i * 16 + quad * 4;
                    #pragma unroll
                    for (int j = 0; j < 4; ++j) {
                        const int dl = j * 16 + col;     // 0..63 within half
                        ushort4 ov;
                        ov.x = f2bf(acc[i][j][0]); ov.y = f2bf(acc[i][j][1]);
                        ov.z = f2bf(acc[i][j][2]); ov.w = f2bf(acc[i][j][3]);
                        *(ushort4*)&Es[dl * 136 + sl] = ov;
                    }
                }
            }
            __syncthreads();
            #pragma unroll
            for (int k = 0; k < 4; ++k) {
                const int c  = tid + k * 256;
                const int dl = c >> 4;               // 0..63 within half
                const int s8 = (c & 15) * 8;
                const int d  = half * 64 + dl;
                const bf16x8 v = *(const bf16x8*)&Es[dl * 136 + s8];
                *(bf16x8*)(Vb + ((size_t)(bb2 * H + hh0 + (d >> 6)) * Dh + (d & 63)) * S
                           + ssb + s8) = v;
            }
        }
    } else {
        // Q/K with fused RoPE from table; Es[row][d] per m-half
        unsigned short* dp = (wsel == 0) ? Qb : Kb;
        const float qscale = (wsel == 0) ? 0.125f : 1.0f;   // D^-0.5 for Q
        #pragma unroll
        for (int half = 0; half < 2; ++half) {
            __syncthreads();
            if ((w & 1) == half) {             // waves whose mw == half*64
                #pragma unroll
                for (int i = 0; i < 4; ++i) {
                    #pragma unroll
                    for (int r = 0; r < 4; ++r) {
                        const int rl = i * 16 + quad * 4 + r;   // 0..63 local
                        const int ss = ssb + half * 64 + rl;
                        const float2 t0 = ((const float2*)Tab)[(size_t)(bb2 * S + ss) * 32 + col];
                        const float2 t1 = ((const float2*)Tab)[(size_t)(bb2 * S + ss) * 32 + col + 16];
                        const float a0 = acc[i][0][r] * qscale, a1 = acc[i][1][r] * qscale;
                        const float a2 = acc[i][2][r] * qscale, a3 = acc[i][3][r] * qscale;
                        unsigned short* e = &Es[rl * 136 + nw];
                        e[col]      = f2bf(a0 * t0.x - a2 * t0.y);
                        e[col + 16] = f2bf(a1 * t1.x - a3 * t1.y);
                        e[col + 32] = f2bf(a2 * t0.x + a0 * t0.y);
                        e[col + 48] = f2bf(a3 * t1.x + a1 * t1.y);
                    }
                }
            }
            __syncthreads();
            #pragma unroll
            for (int k = 0; k < 4; ++k) {
                const int c  = tid + k * 256;
                const int rl = c >> 4;               // 0..63 local row
                const int d8 = (c & 15) * 8;
                const bf16x8 v = *(const bf16x8*)&Es[rl * 136 + d8];
                *(bf16x8*)(dp + ((size_t)(bb2 * H + hh0 + (d8 >> 6)) * S
                                 + ssb + half * 64 + rl) * Dh + (d8 & 63)) = v;
            }
        }
    }
}

// ---------------------------------------------------------------------------
// Kernel 2: flash attention — round-0 verified version (best: 92 µs).
//   Double-buffered K/V register prefetch, one barrier per tile; V
//   pre-transposed [B,H,Dh,S]; mask loads double-buffered (prefetched one
//   tile ahead with K/V). U=2 (32 q/wave), static-shift softmax, b64-packed
//   P̃ stores. grid = (S/128, B*H) = 512 blocks, 256 thr.
// ---------------------------------------------------------------------------
#define KSd 72
#define SHIFT_C 8.0f
#define NT (S / 64)

__global__ __launch_bounds__(256) void attn_kernel(const unsigned short* __restrict__ Q,
                                                   const unsigned short* __restrict__ K,
                                                   const unsigned short* __restrict__ V,
                                                   const float* __restrict__ mask,
                                                   float* __restrict__ out) {
    __shared__ __align__(16) unsigned short Ks[2][64 * KSd];   // [key][d]
    __shared__ __align__(16) unsigned short Vt[2][64 * KSd];   // [d][key]
    __shared__ __align__(16) unsigned short Ps[4 * 32 * KSd];

    const int tid  = threadIdx.x;
    const int w    = tid >> 6;
    const int lane = tid & 63;
    const int col  = lane & 15;
    const int quad = lane >> 4;
    const int bh   = blockIdx.y;
    const int b    = bh >> 4, h = bh & 15;
    const int q0   = blockIdx.x * 128;
    const int qw   = q0 + w * 32;             // wave's q base (32 rows)

    const int srow = tid >> 3;            // 0..31
    const int sc8  = (tid & 7) * 8;

    // Q fragments: qa[u][kc] — lane holds Q[q=qw+u*16+col][kc*32+quad*8 ..+7]
    bf16x8 qa[2][2];
    #pragma unroll
    for (int u = 0; u < 2; ++u) {
        const unsigned short* qrow = Q + ((size_t)bh * S + qw + u * 16 + col) * Dh;
        qa[u][0] = *(const bf16x8*)(qrow + quad * 8);
        qa[u][1] = *(const bf16x8*)(qrow + 32 + quad * 8);
    }

    f32x4 o[4][2] = {};                        // O^T frags: [d-frag g][q-frag u]
    float lsum[2] = {0.f, 0.f};
    const float* mbase = mask + (size_t)b * S * S;
    unsigned short* pw = Ps + w * 32 * KSd;
    const unsigned short* Kbase = K + (size_t)bh * S * Dh;
    const unsigned short* Vbase = V + (size_t)bh * Dh * S;   // transposed

    // ---- prologue: tile-0 K/V + mask into regs, stage K/V into buffer 0 ----
    bf16x8 kp[2], vp[2];
    float4 mv[4][2];
    #pragma unroll
    for (int cc = 0; cc < 2; ++cc) {
        kp[cc] = *(const bf16x8*)(Kbase + (size_t)(srow + cc * 32) * Dh + sc8);
        vp[cc] = *(const bf16x8*)(Vbase + (size_t)(srow + cc * 32) * S + sc8);
    }
    #pragma unroll
    for (int u = 0; u < 2; ++u)
        #pragma unroll
        for (int f = 0; f < 4; ++f)
            mv[f][u] = *(const float4*)(mbase + (size_t)(qw + u * 16 + col) * S
                                        + f * 16 + quad * 4);
    #pragma unroll
    for (int cc = 0; cc < 2; ++cc) {
        const int row = srow + cc * 32;
        *(bf16x8*)&Ks[0][row * KSd + sc8] = kp[cc];
        *(bf16x8*)&Vt[0][row * KSd + sc8] = vp[cc];
    }
    __syncthreads();

    for (int kt = 0; kt < NT; ++kt) {
        const int cur = kt & 1;

        // ---- issue prefetch loads for tile kt+1 (no wait): K/V + mask ----
        float4 mvp[4][2];
        if (kt + 1 < NT) {
            #pragma unroll
            for (int cc = 0; cc < 2; ++cc) {
                kp[cc] = *(const bf16x8*)(Kbase + (size_t)((kt + 1) * 64 + srow + cc * 32) * Dh + sc8);
                vp[cc] = *(const bf16x8*)(Vbase + (size_t)(srow + cc * 32) * S + (kt + 1) * 64 + sc8);
            }
            #pragma unroll
            for (int u = 0; u < 2; ++u)
                #pragma unroll
                for (int f = 0; f < 4; ++f)
                    mvp[f][u] = *(const float4*)(mbase + (size_t)(qw + u * 16 + col) * S
                                                 + (kt + 1) * 64 + f * 16 + quad * 4);
        }

        // ---- S^T = K · Q^T : C[m=key][n=q] ----
        f32x4 sc[4][2] = {};
        #pragma unroll
        for (int f = 0; f < 4; ++f) {
            const bf16x8 ka0 = *(const bf16x8*)&Ks[cur][(f * 16 + col) * KSd + quad * 8];
            const bf16x8 ka1 = *(const bf16x8*)&Ks[cur][(f * 16 + col) * KSd + 32 + quad * 8];
            #pragma unroll
            for (int u = 0; u < 2; ++u) {
                sc[f][u] = __builtin_amdgcn_mfma_f32_16x16x32_bf16(ka0, qa[u][0], sc[f][u], 0, 0, 0);
                sc[f][u] = __builtin_amdgcn_mfma_f32_16x16x32_bf16(ka1, qa[u][1], sc[f][u], 0, 0, 0);
            }
        }

        // ---- static-shift softmax numerator + packed P̃ store ----
        #pragma unroll
        for (int u = 0; u < 2; ++u) {
            #pragma unroll
            for (int f = 0; f < 4; ++f) {
                sc[f][u][0] += mv[f][u].x; sc[f][u][1] += mv[f][u].y;
                sc[f][u][2] += mv[f][u].z; sc[f][u][3] += mv[f][u].w;
            }
            #pragma unroll
            for (int f = 0; f < 4; ++f)
                #pragma unroll
                for (int r = 0; r < 4; ++r) {
                    const float pv = __expf(sc[f][u][r] - SHIFT_C);
                    sc[f][u][r] = pv;
                    lsum[u] += pv;
                }
            unsigned short* pq = pw + (u * 16 + col) * KSd;
            #pragma unroll
            for (int f = 0; f < 4; ++f) {
                const unsigned v0 = (unsigned)f2bf(sc[f][u][0]) | ((unsigned)f2bf(sc[f][u][1]) << 16);
                const unsigned v1 = (unsigned)f2bf(sc[f][u][2]) | ((unsigned)f2bf(sc[f][u][3]) << 16);
                *(uint2*)&pq[f * 16 + quad * 4] = make_uint2(v0, v1);
            }
        }

        // ---- rotate mask buffers; drain K/V prefetch into other LDS buffer ----
        if (kt + 1 < NT) {
            #pragma unroll
            for (int u = 0; u < 2; ++u)
                #pragma unroll
                for (int f = 0; f < 4; ++f)
                    mv[f][u] = mvp[f][u];
            const int nxt = cur ^ 1;
            #pragma unroll
            for (int cc = 0; cc < 2; ++cc) {
                const int row = srow + cc * 32;
                *(bf16x8*)&Ks[nxt][row * KSd + sc8] = kp[cc];
                *(bf16x8*)&Vt[nxt][row * KSd + sc8] = vp[cc];
            }
        }
        __threadfence_block();   // wave-private Ps visible before PV reads

        // ---- O^T += V^T · P̃ ----
        #pragma unroll
        for (int kc = 0; kc < 2; ++kc) {
            bf16x8 pb[2];
            #pragma unroll
            for (int u = 0; u < 2; ++u)
                pb[u] = *(const bf16x8*)&pw[(u * 16 + col) * KSd + kc * 32 + quad * 8];
            #pragma unroll
            for (int g = 0; g < 4; ++g) {
                const bf16x8 va = *(const bf16x8*)&Vt[cur][(g * 16 + col) * KSd + kc * 32 + quad * 8];
                #pragma unroll
                for (int u = 0; u < 2; ++u)
                    o[g][u] = __builtin_amdgcn_mfma_f32_16x16x32_bf16(va, pb[u], o[g][u], 0, 0, 0);
            }
        }
        __syncthreads();   // single barrier: iter kt writes->nxt, reads->cur
    }

    // ---- deferred l reduction (quads hold disjoint key subsets) ----
    #pragma unroll
    for (int u = 0; u < 2; ++u) {
        lsum[u] += __shfl_xor(lsum[u], 16, 64);
        lsum[u] += __shfl_xor(lsum[u], 32, 64);
    }

    // ---- epilogue: lane (quad,r,col) holds O[q=qw+u*16+col][d=g*16+quad*4+r]
    #pragma unroll
    for (int u = 0; u < 2; ++u) {
        const float inv = 1.f / lsum[u];
        float* op = out + ((size_t)b * S + qw + u * 16 + col) * DM + h * Dh + quad * 4;
        #pragma unroll
        for (int g = 0; g < 4; ++g) {
            float4 ov;
            ov.x = o[g][u][0] * inv; ov.y = o[g][u][1] * inv;
            ov.z = o[g][u][2] * inv; ov.w = o[g][u][3] * inv;
            *(float4*)(op + g * 16) = ov;
        }
    }
}

// ---------------------------------------------------------------------------
extern "C" void kernel_launch(void* const* d_in, const int* in_sizes, int n_in,
                              void* d_out, int out_size, void* d_ws, size_t ws_size,
                              hipStream_t stream) {
    const float* hs   = (const float*)d_in[0];  // (B,S,DM)
    const float* mask = (const float*)d_in[1];  // (B,1,S,S)
    const int*   pos  = (const int*)  d_in[2];  // (B,S)
    const float* Wq   = (const float*)d_in[3];
    const float* Wk   = (const float*)d_in[4];
    const float* Wv   = (const float*)d_in[5];
    float* out = (float*)d_out;

    // workspace (ushort units): Xb 4,194,304 | Wb 3,145,728 |
    //   Qb,Kb [B,H,S,Dh], Vb [B,H,Dh,S] each 4,194,304 | Tab 1 MB (float2)
    unsigned short* Xb = (unsigned short*)d_ws;
    unsigned short* Wb = Xb + 4194304;
    unsigned short* Qb = Wb + 3145728;
    unsigned short* Kb = Qb + 4194304;
    unsigned short* Vb = Kb + 4194304;
    float*          Tab = (float*)(Vb + 4194304);   // 262144 floats

    cast_kernel<<<7168, 256, 0, stream>>>(hs, Wq, Wk, Wv, Xb, Wb);
    rope_tab_kernel<<<512, 256, 0, stream>>>(pos, Tab);
    qkv_gemm<<<dim3(32, 24), 256, 0, stream>>>(Xb, Wb, Tab, Qb, Kb, Vb);
    attn_kernel<<<dim3(S / 128, BH), 256, 0, stream>>>(Qb, Kb, Vb, mask, out);
}

// Round 4
// 225.275 us; speedup vs baseline: 1.0886x; 1.0886x over previous
//
#include <hip/hip_runtime.h>
#include <math.h>

// Problem constants (from reference)
#define B  2
#define S  2048
#define DM 1024
#define H  16
#define Dh 64
#define BH (B*H)

typedef short  bf16x8 __attribute__((ext_vector_type(8)));
typedef float  f32x4  __attribute__((ext_vector_type(4)));

__device__ __forceinline__ unsigned short f2bf(float f) {
    unsigned u = __float_as_uint(f);
    u = (u + 0x7fffu + ((u >> 16) & 1u)) >> 16;   // RNE, no NaN inputs here
    return (unsigned short)u;
}

// gfx950 packed f32->bf16 (RNE) — replaces two 4-op bit-trick converts + pack
// with ONE VALU instruction. Used only in the attn hot loop this round.
__device__ __forceinline__ unsigned cvt_pk_bf16(float lo, float hi) {
    unsigned r;
    asm("v_cvt_pk_bf16_f32 %0, %1, %2" : "=v"(r) : "v"(lo), "v"(hi));
    return r;
}

// ---------------------------------------------------------------------------
// Kernel 0a: cast hidden_states + Wq|Wk|Wv (fp32) to bf16 workspace buffers.
// ---------------------------------------------------------------------------
__global__ __launch_bounds__(256) void cast_kernel(const float* __restrict__ X,
                                                   const float* __restrict__ Wq,
                                                   const float* __restrict__ Wk,
                                                   const float* __restrict__ Wv,
                                                   unsigned short* __restrict__ Xb,
                                                   unsigned short* __restrict__ Wb) {
    const long c = (long)(blockIdx.x * 256 + threadIdx.x) * 4;
    const float* src;
    unsigned short* dst;
    if (c < 4194304L) {
        src = X + c;  dst = Xb + c;
    } else {
        const long c2 = c - 4194304L;
        const int  wi = (int)(c2 >> 20);
        const long r  = c2 & 1048575L;
        src = (wi == 0 ? Wq : (wi == 1 ? Wk : Wv)) + r;
        dst = Wb + c2;
    }
    const float4 v = *(const float4*)src;
    ushort4 o;
    o.x = f2bf(v.x); o.y = f2bf(v.y); o.z = f2bf(v.z); o.w = f2bf(v.w);
    *(ushort4*)dst = o;
}

// ---------------------------------------------------------------------------
// Kernel 0b: RoPE cos/sin table: Tab[(b*S+s)*32 + i] = (cos, sin) of
//   pos[b,s] * 10000^(-i/32).  1 MB, L2-resident.
// ---------------------------------------------------------------------------
__global__ __launch_bounds__(256) void rope_tab_kernel(const int* __restrict__ pos,
                                                       float* __restrict__ Tab) {
    const int idx = blockIdx.x * 256 + threadIdx.x;   // < B*S*32 = 131072
    const int i  = idx & 31;
    const int bs = idx >> 5;
    const float p   = (float)pos[bs];
    const float inv = exp2f(-(float)i * 0.41524101186092029f);  // log2(1e4)/32
    float sn, cs;
    sincosf(p * inv, &sn, &cs);
    ((float2*)Tab)[idx] = make_float2(cs, sn);
}

// async global->LDS, 16B per lane
__device__ __forceinline__ void gload_lds16(const unsigned short* g, unsigned short* l) {
    __builtin_amdgcn_global_load_lds(
        (const __attribute__((address_space(1))) unsigned int*)g,
        (__attribute__((address_space(3))) unsigned int*)l,
        16, 0, 0);
}

// ---------------------------------------------------------------------------
// Kernel 1: fused QKV GEMM (R0 verified config: BK=32, 16 MFMA/barrier —
//   BK=64 regressed −19 µs in R3). global_load_lds staging with XOR chunk
//   swizzle. Epilogue: RoPE via table + LDS round-trip (Es, 2 halves) so ALL
//   global stores are coalesced 16B. V written transposed [B,H,Dh,S].
// ---------------------------------------------------------------------------
__global__ __launch_bounds__(256) void qkv_gemm(const unsigned short* __restrict__ Xb,
                                                const unsigned short* __restrict__ Wb,
                                                const float* __restrict__ Tab,
                                                unsigned short* __restrict__ Qb,
                                                unsigned short* __restrict__ Kb,
                                                unsigned short* __restrict__ Vb) {
    __shared__ __align__(16) unsigned short As[128 * 32];
    __shared__ __align__(16) unsigned short Bs[128 * 32];
    __shared__ __align__(16) unsigned short Es[64 * 136];   // epilogue staging

    const int tid  = threadIdx.x;
    const int w    = tid >> 6;
    const int lane = tid & 63;
    const int col  = lane & 15;
    const int quad = lane >> 4;
    const int m0 = blockIdx.x * 128;
    const int n0 = blockIdx.y * 128;
    const int mw = (w & 1) * 64;
    const int nw = (w >> 1) * 64;

    // staging: lane i loads row i>>2, global chunk (i&3)^(row&3)  (XOR swizzle)
    const int srow = lane >> 2;
    const int sk8  = (((lane & 3) ^ (srow & 3))) * 8;

    f32x4 acc[4][4] = {};

    for (int k0 = 0; k0 < 1024; k0 += 32) {
        __syncthreads();
        #pragma unroll
        for (int it = 0; it < 2; ++it) {
            const int rbase = w * 16 + it * 64;
            gload_lds16(Xb + (size_t)(m0 + rbase + srow) * 1024 + k0 + sk8,
                        &As[rbase * 32]);
            gload_lds16(Wb + (size_t)(n0 + rbase + srow) * 1024 + k0 + sk8,
                        &Bs[rbase * 32]);
        }
        __syncthreads();

        // global k-chunk quad lives at LDS slot quad^(row&3); row&3 == col&3
        const int fs = (quad ^ (col & 3)) * 8;
        bf16x8 a[4], bb[4];
        #pragma unroll
        for (int i = 0; i < 4; ++i)
            a[i] = *(const bf16x8*)&As[(mw + i * 16 + col) * 32 + fs];
        #pragma unroll
        for (int j = 0; j < 4; ++j)
            bb[j] = *(const bf16x8*)&Bs[(nw + j * 16 + col) * 32 + fs];
        #pragma unroll
        for (int i = 0; i < 4; ++i)
            #pragma unroll
            for (int j = 0; j < 4; ++j)
                acc[i][j] = __builtin_amdgcn_mfma_f32_16x16x32_bf16(a[i], bb[j], acc[i][j], 0, 0, 0);
    }

    // ---- epilogue ----
    const int wsel = n0 >> 10;                 // 0=Q, 1=K, 2=V
    const int hh0  = (n0 & 1023) >> 6;         // base head of this n-tile
    const int bb2  = m0 >> 11;                 // batch (block never straddles)
    const int ssb  = m0 & 2047;                // seq base

    if (wsel == 2) {
        // V -> [B,H,Dh,S]; Es[dl][ssl] per dcol-half, b64 packed writes
        #pragma unroll
        for (int half = 0; half < 2; ++half) {
            __syncthreads();
            if ((w >> 1) == half) {            // waves whose nw == half*64
                #pragma unroll
                for (int i = 0; i < 4; ++i) {
                    const int sl = mw + i * 16 + quad * 4;
                    #pragma unroll
                    for (int j = 0; j < 4; ++j) {
                        const int dl = j * 16 + col;     // 0..63 within half
                        ushort4 ov;
                        ov.x = f2bf(acc[i][j][0]); ov.y = f2bf(acc[i][j][1]);
                        ov.z = f2bf(acc[i][j][2]); ov.w = f2bf(acc[i][j][3]);
                        *(ushort4*)&Es[dl * 136 + sl] = ov;
                    }
                }
            }
            __syncthreads();
            #pragma unroll
            for (int k = 0; k < 4; ++k) {
                const int c  = tid + k * 256;
                const int dl = c >> 4;               // 0..63 within half
                const int s8 = (c & 15) * 8;
                const int d  = half * 64 + dl;
                const bf16x8 v = *(const bf16x8*)&Es[dl * 136 + s8];
                *(bf16x8*)(Vb + ((size_t)(bb2 * H + hh0 + (d >> 6)) * Dh + (d & 63)) * S
                           + ssb + s8) = v;
            }
        }
    } else {
        // Q/K with fused RoPE from table; Es[row][d] per m-half
        unsigned short* dp = (wsel == 0) ? Qb : Kb;
        const float qscale = (wsel == 0) ? 0.125f : 1.0f;   // D^-0.5 for Q
        #pragma unroll
        for (int half = 0; half < 2; ++half) {
            __syncthreads();
            if ((w & 1) == half) {             // waves whose mw == half*64
                #pragma unroll
                for (int i = 0; i < 4; ++i) {
                    #pragma unroll
                    for (int r = 0; r < 4; ++r) {
                        const int rl = i * 16 + quad * 4 + r;   // 0..63 local
                        const int ss = ssb + half * 64 + rl;
                        const float2 t0 = ((const float2*)Tab)[(size_t)(bb2 * S + ss) * 32 + col];
                        const float2 t1 = ((const float2*)Tab)[(size_t)(bb2 * S + ss) * 32 + col + 16];
                        const float a0 = acc[i][0][r] * qscale, a1 = acc[i][1][r] * qscale;
                        const float a2 = acc[i][2][r] * qscale, a3 = acc[i][3][r] * qscale;
                        unsigned short* e = &Es[rl * 136 + nw];
                        e[col]      = f2bf(a0 * t0.x - a2 * t0.y);
                        e[col + 16] = f2bf(a1 * t1.x - a3 * t1.y);
                        e[col + 32] = f2bf(a2 * t0.x + a0 * t0.y);
                        e[col + 48] = f2bf(a3 * t1.x + a1 * t1.y);
                    }
                }
            }
            __syncthreads();
            #pragma unroll
            for (int k = 0; k < 4; ++k) {
                const int c  = tid + k * 256;
                const int rl = c >> 4;               // 0..63 local row
                const int d8 = (c & 15) * 8;
                const bf16x8 v = *(const bf16x8*)&Es[rl * 136 + d8];
                *(bf16x8*)(dp + ((size_t)(bb2 * H + hh0 + (d8 >> 6)) * S
                                 + ssb + half * 64 + rl) * Dh + (d8 & 63)) = v;
            }
        }
    }
}

// ---------------------------------------------------------------------------
// Kernel 2: flash attention — R0 structure EXACTLY (double-buffered K/V
//   register prefetch, one barrier/tile, mask prefetch, U=2, static-shift
//   softmax). This round's ONLY changes (isolated VALU cut, must keep
//   VGPR <= 128 — R1's regression was the 136-VGPR occupancy cliff):
//   (a) P̃ pack via v_cvt_pk_bf16_f32 (72 -> 8 ops/tile),
//   (b) __expf(x-8) -> v_exp(fma(x, log2e, -8*log2e)) (3 -> 2 ops/elem).
//   grid = (S/128, B*H) = 512 blocks, 256 thr.
// ---------------------------------------------------------------------------
#define KSd 72
#define LOG2E  1.4426950408889634f
#define NEG8L (-11.541560327111707f)      // -8 * log2(e); exp(s-8) == exp2(fma)
#define NT (S / 64)

__global__ __launch_bounds__(256) void attn_kernel(const unsigned short* __restrict__ Q,
                                                   const unsigned short* __restrict__ K,
                                                   const unsigned short* __restrict__ V,
                                                   const float* __restrict__ mask,
                                                   float* __restrict__ out) {
    __shared__ __align__(16) unsigned short Ks[2][64 * KSd];   // [key][d]
    __shared__ __align__(16) unsigned short Vt[2][64 * KSd];   // [d][key]
    __shared__ __align__(16) unsigned short Ps[4 * 32 * KSd];

    const int tid  = threadIdx.x;
    const int w    = tid >> 6;
    const int lane = tid & 63;
    const int col  = lane & 15;
    const int quad = lane >> 4;
    const int bh   = blockIdx.y;
    const int b    = bh >> 4, h = bh & 15;
    const int q0   = blockIdx.x * 128;
    const int qw   = q0 + w * 32;             // wave's q base (32 rows)

    const int srow = tid >> 3;            // 0..31
    const int sc8  = (tid & 7) * 8;

    // Q fragments: qa[u][kc] — lane holds Q[q=qw+u*16+col][kc*32+quad*8 ..+7]
    bf16x8 qa[2][2];
    #pragma unroll
    for (int u = 0; u < 2; ++u) {
        const unsigned short* qrow = Q + ((size_t)bh * S + qw + u * 16 + col) * Dh;
        qa[u][0] = *(const bf16x8*)(qrow + quad * 8);
        qa[u][1] = *(const bf16x8*)(qrow + 32 + quad * 8);
    }

    f32x4 o[4][2] = {};                        // O^T frags: [d-frag g][q-frag u]
    float lsum[2] = {0.f, 0.f};
    const float* mbase = mask + (size_t)b * S * S;
    unsigned short* pw = Ps + w * 32 * KSd;
    const unsigned short* Kbase = K + (size_t)bh * S * Dh;
    const unsigned short* Vbase = V + (size_t)bh * Dh * S;   // transposed

    // ---- prologue: tile-0 K/V + mask into regs, stage K/V into buffer 0 ----
    bf16x8 kp[2], vp[2];
    float4 mv[4][2];
    #pragma unroll
    for (int cc = 0; cc < 2; ++cc) {
        kp[cc] = *(const bf16x8*)(Kbase + (size_t)(srow + cc * 32) * Dh + sc8);
        vp[cc] = *(const bf16x8*)(Vbase + (size_t)(srow + cc * 32) * S + sc8);
    }
    #pragma unroll
    for (int u = 0; u < 2; ++u)
        #pragma unroll
        for (int f = 0; f < 4; ++f)
            mv[f][u] = *(const float4*)(mbase + (size_t)(qw + u * 16 + col) * S
                                        + f * 16 + quad * 4);
    #pragma unroll
    for (int cc = 0; cc < 2; ++cc) {
        const int row = srow + cc * 32;
        *(bf16x8*)&Ks[0][row * KSd + sc8] = kp[cc];
        *(bf16x8*)&Vt[0][row * KSd + sc8] = vp[cc];
    }
    __syncthreads();

    for (int kt = 0; kt < NT; ++kt) {
        const int cur = kt & 1;

        // ---- issue prefetch loads for tile kt+1 (no wait): K/V + mask ----
        float4 mvp[4][2];
        if (kt + 1 < NT) {
            #pragma unroll
            for (int cc = 0; cc < 2; ++cc) {
                kp[cc] = *(const bf16x8*)(Kbase + (size_t)((kt + 1) * 64 + srow + cc * 32) * Dh + sc8);
                vp[cc] = *(const bf16x8*)(Vbase + (size_t)(srow + cc * 32) * S + (kt + 1) * 64 + sc8);
            }
            #pragma unroll
            for (int u = 0; u < 2; ++u)
                #pragma unroll
                for (int f = 0; f < 4; ++f)
                    mvp[f][u] = *(const float4*)(mbase + (size_t)(qw + u * 16 + col) * S
                                                 + (kt + 1) * 64 + f * 16 + quad * 4);
        }

        // ---- S^T = K · Q^T : C[m=key][n=q] ----
        f32x4 sc[4][2] = {};
        #pragma unroll
        for (int f = 0; f < 4; ++f) {
            const bf16x8 ka0 = *(const bf16x8*)&Ks[cur][(f * 16 + col) * KSd + quad * 8];
            const bf16x8 ka1 = *(const bf16x8*)&Ks[cur][(f * 16 + col) * KSd + 32 + quad * 8];
            #pragma unroll
            for (int u = 0; u < 2; ++u) {
                sc[f][u] = __builtin_amdgcn_mfma_f32_16x16x32_bf16(ka0, qa[u][0], sc[f][u], 0, 0, 0);
                sc[f][u] = __builtin_amdgcn_mfma_f32_16x16x32_bf16(ka1, qa[u][1], sc[f][u], 0, 0, 0);
            }
        }

        // ---- static-shift softmax numerator + packed P̃ store ----
        #pragma unroll
        for (int u = 0; u < 2; ++u) {
            #pragma unroll
            for (int f = 0; f < 4; ++f) {
                sc[f][u][0] += mv[f][u].x; sc[f][u][1] += mv[f][u].y;
                sc[f][u][2] += mv[f][u].z; sc[f][u][3] += mv[f][u].w;
            }
            #pragma unroll
            for (int f = 0; f < 4; ++f)
                #pragma unroll
                for (int r = 0; r < 4; ++r) {
                    const float pv = __builtin_amdgcn_exp2f(
                        __builtin_fmaf(sc[f][u][r], LOG2E, NEG8L));
                    sc[f][u][r] = pv;
                    lsum[u] += pv;
                }
            unsigned short* pq = pw + (u * 16 + col) * KSd;
            #pragma unroll
            for (int f = 0; f < 4; ++f) {
                *(uint2*)&pq[f * 16 + quad * 4] =
                    make_uint2(cvt_pk_bf16(sc[f][u][0], sc[f][u][1]),
                               cvt_pk_bf16(sc[f][u][2], sc[f][u][3]));
            }
        }

        // ---- rotate mask buffers; drain K/V prefetch into other LDS buffer ----
        if (kt + 1 < NT) {
            #pragma unroll
            for (int u = 0; u < 2; ++u)
                #pragma unroll
                for (int f = 0; f < 4; ++f)
                    mv[f][u] = mvp[f][u];
            const int nxt = cur ^ 1;
            #pragma unroll
            for (int cc = 0; cc < 2; ++cc) {
                const int row = srow + cc * 32;
                *(bf16x8*)&Ks[nxt][row * KSd + sc8] = kp[cc];
                *(bf16x8*)&Vt[nxt][row * KSd + sc8] = vp[cc];
            }
        }
        __threadfence_block();   // wave-private Ps visible before PV reads

        // ---- O^T += V^T · P̃ ----
        #pragma unroll
        for (int kc = 0; kc < 2; ++kc) {
            bf16x8 pb[2];
            #pragma unroll
            for (int u = 0; u < 2; ++u)
                pb[u] = *(const bf16x8*)&pw[(u * 16 + col) * KSd + kc * 32 + quad * 8];
            #pragma unroll
            for (int g = 0; g < 4; ++g) {
                const bf16x8 va = *(const bf16x8*)&Vt[cur][(g * 16 + col) * KSd + kc * 32 + quad * 8];
                #pragma unroll
                for (int u = 0; u < 2; ++u)
                    o[g][u] = __builtin_amdgcn_mfma_f32_16x16x32_bf16(va, pb[u], o[g][u], 0, 0, 0);
            }
        }
        __syncthreads();   // single barrier: iter kt writes->nxt, reads->cur
    }

    // ---- deferred l reduction (quads hold disjoint key subsets) ----
    #pragma unroll
    for (int u = 0; u < 2; ++u) {
        lsum[u] += __shfl_xor(lsum[u], 16, 64);
        lsum[u] += __shfl_xor(lsum[u], 32, 64);
    }

    // ---- epilogue: lane (quad,r,col) holds O[q=qw+u*16+col][d=g*16+quad*4+r]
    #pragma unroll
    for (int u = 0; u < 2; ++u) {
        const float inv = 1.f / lsum[u];
        float* op = out + ((size_t)b * S + qw + u * 16 + col) * DM + h * Dh + quad * 4;
        #pragma unroll
        for (int g = 0; g < 4; ++g) {
            float4 ov;
            ov.x = o[g][u][0] * inv; ov.y = o[g][u][1] * inv;
            ov.z = o[g][u][2] * inv; ov.w = o[g][u][3] * inv;
            *(float4*)(op + g * 16) = ov;
        }
    }
}

// ---------------------------------------------------------------------------
extern "C" void kernel_launch(void* const* d_in, const int* in_sizes, int n_in,
                              void* d_out, int out_size, void* d_ws, size_t ws_size,
                              hipStream_t stream) {
    const float* hs   = (const float*)d_in[0];  // (B,S,DM)
    const float* mask = (const float*)d_in[1];  // (B,1,S,S)
    const int*   pos  = (const int*)  d_in[2];  // (B,S)
    const float* Wq   = (const float*)d_in[3];
    const float* Wk   = (const float*)d_in[4];
    const float* Wv   = (const float*)d_in[5];
    float* out = (float*)d_out;

    // workspace (ushort units): Xb 4,194,304 | Wb 3,145,728 |
    //   Qb,Kb [B,H,S,Dh], Vb [B,H,Dh,S] each 4,194,304 | Tab 1 MB (float2)
    unsigned short* Xb = (unsigned short*)d_ws;
    unsigned short* Wb = Xb + 4194304;
    unsigned short* Qb = Wb + 3145728;
    unsigned short* Kb = Qb + 4194304;
    unsigned short* Vb = Kb + 4194304;
    float*          Tab = (float*)(Vb + 4194304);   // 262144 floats

    cast_kernel<<<7168, 256, 0, stream>>>(hs, Wq, Wk, Wv, Xb, Wb);
    rope_tab_kernel<<<512, 256, 0, stream>>>(pos, Tab);
    qkv_gemm<<<dim3(32, 24), 256, 0, stream>>>(Xb, Wb, Tab, Qb, Kb, Vb);
    attn_kernel<<<dim3(S / 128, BH), 256, 0, stream>>>(Qb, Kb, Vb, mask, out);
}

// Round 5
// 222.485 us; speedup vs baseline: 1.1023x; 1.0125x over previous
//
#include <hip/hip_runtime.h>
#include <math.h>

// Problem constants (from reference)
#define B  2
#define S  2048
#define DM 1024
#define H  16
#define Dh 64
#define BH (B*H)

typedef short  bf16x8 __attribute__((ext_vector_type(8)));
typedef float  f32x4  __attribute__((ext_vector_type(4)));

__device__ __forceinline__ unsigned short f2bf(float f) {
    unsigned u = __float_as_uint(f);
    u = (u + 0x7fffu + ((u >> 16) & 1u)) >> 16;   // RNE, no NaN inputs here
    return (unsigned short)u;
}

// gfx950 packed f32->bf16 (RNE) — one VALU op for two converts+pack.
__device__ __forceinline__ unsigned cvt_pk_bf16(float lo, float hi) {
    unsigned r;
    asm("v_cvt_pk_bf16_f32 %0, %1, %2" : "=v"(r) : "v"(lo), "v"(hi));
    return r;
}

// ---------------------------------------------------------------------------
// Kernel 0a: cast hidden_states + Wq|Wk|Wv (fp32) to bf16 workspace buffers.
// ---------------------------------------------------------------------------
__global__ __launch_bounds__(256) void cast_kernel(const float* __restrict__ X,
                                                   const float* __restrict__ Wq,
                                                   const float* __restrict__ Wk,
                                                   const float* __restrict__ Wv,
                                                   unsigned short* __restrict__ Xb,
                                                   unsigned short* __restrict__ Wb) {
    const long c = (long)(blockIdx.x * 256 + threadIdx.x) * 4;
    const float* src;
    unsigned short* dst;
    if (c < 4194304L) {
        src = X + c;  dst = Xb + c;
    } else {
        const long c2 = c - 4194304L;
        const int  wi = (int)(c2 >> 20);
        const long r  = c2 & 1048575L;
        src = (wi == 0 ? Wq : (wi == 1 ? Wk : Wv)) + r;
        dst = Wb + c2;
    }
    const float4 v = *(const float4*)src;
    ushort4 o;
    o.x = f2bf(v.x); o.y = f2bf(v.y); o.z = f2bf(v.z); o.w = f2bf(v.w);
    *(ushort4*)dst = o;
}

// ---------------------------------------------------------------------------
// Kernel 0b: RoPE cos/sin table: Tab[(b*S+s)*32 + i] = (cos, sin) of
//   pos[b,s] * 10000^(-i/32).  1 MB, L2-resident.
// ---------------------------------------------------------------------------
__global__ __launch_bounds__(256) void rope_tab_kernel(const int* __restrict__ pos,
                                                       float* __restrict__ Tab) {
    const int idx = blockIdx.x * 256 + threadIdx.x;   // < B*S*32 = 131072
    const int i  = idx & 31;
    const int bs = idx >> 5;
    const float p   = (float)pos[bs];
    const float inv = exp2f(-(float)i * 0.41524101186092029f);  // log2(1e4)/32
    float sn, cs;
    sincosf(p * inv, &sn, &cs);
    ((float2*)Tab)[idx] = make_float2(cs, sn);
}

// async global->LDS, 16B per lane
__device__ __forceinline__ void gload_lds16(const unsigned short* g, unsigned short* l) {
    __builtin_amdgcn_global_load_lds(
        (const __attribute__((address_space(1))) unsigned int*)g,
        (__attribute__((address_space(3))) unsigned int*)l,
        16, 0, 0);
}

// ---------------------------------------------------------------------------
// Kernel 1: fused QKV GEMM (R0 verified config: BK=32, 16 MFMA/barrier —
//   BK=64 regressed −19 µs in R3). global_load_lds staging with XOR chunk
//   swizzle. Epilogue: RoPE via table + LDS round-trip (Es, 2 halves) so ALL
//   global stores are coalesced 16B. V written transposed [B,H,Dh,S].
// ---------------------------------------------------------------------------
__global__ __launch_bounds__(256) void qkv_gemm(const unsigned short* __restrict__ Xb,
                                                const unsigned short* __restrict__ Wb,
                                                const float* __restrict__ Tab,
                                                unsigned short* __restrict__ Qb,
                                                unsigned short* __restrict__ Kb,
                                                unsigned short* __restrict__ Vb) {
    __shared__ __align__(16) unsigned short As[128 * 32];
    __shared__ __align__(16) unsigned short Bs[128 * 32];
    __shared__ __align__(16) unsigned short Es[64 * 136];   // epilogue staging

    const int tid  = threadIdx.x;
    const int w    = tid >> 6;
    const int lane = tid & 63;
    const int col  = lane & 15;
    const int quad = lane >> 4;
    const int m0 = blockIdx.x * 128;
    const int n0 = blockIdx.y * 128;
    const int mw = (w & 1) * 64;
    const int nw = (w >> 1) * 64;

    // staging: lane i loads row i>>2, global chunk (i&3)^(row&3)  (XOR swizzle)
    const int srow = lane >> 2;
    const int sk8  = (((lane & 3) ^ (srow & 3))) * 8;

    f32x4 acc[4][4] = {};

    for (int k0 = 0; k0 < 1024; k0 += 32) {
        __syncthreads();
        #pragma unroll
        for (int it = 0; it < 2; ++it) {
            const int rbase = w * 16 + it * 64;
            gload_lds16(Xb + (size_t)(m0 + rbase + srow) * 1024 + k0 + sk8,
                        &As[rbase * 32]);
            gload_lds16(Wb + (size_t)(n0 + rbase + srow) * 1024 + k0 + sk8,
                        &Bs[rbase * 32]);
        }
        __syncthreads();

        // global k-chunk quad lives at LDS slot quad^(row&3); row&3 == col&3
        const int fs = (quad ^ (col & 3)) * 8;
        bf16x8 a[4], bb[4];
        #pragma unroll
        for (int i = 0; i < 4; ++i)
            a[i] = *(const bf16x8*)&As[(mw + i * 16 + col) * 32 + fs];
        #pragma unroll
        for (int j = 0; j < 4; ++j)
            bb[j] = *(const bf16x8*)&Bs[(nw + j * 16 + col) * 32 + fs];
        #pragma unroll
        for (int i = 0; i < 4; ++i)
            #pragma unroll
            for (int j = 0; j < 4; ++j)
                acc[i][j] = __builtin_amdgcn_mfma_f32_16x16x32_bf16(a[i], bb[j], acc[i][j], 0, 0, 0);
    }

    // ---- epilogue ----
    const int wsel = n0 >> 10;                 // 0=Q, 1=K, 2=V
    const int hh0  = (n0 & 1023) >> 6;         // base head of this n-tile
    const int bb2  = m0 >> 11;                 // batch (block never straddles)
    const int ssb  = m0 & 2047;                // seq base

    if (wsel == 2) {
        // V -> [B,H,Dh,S]; Es[dl][ssl] per dcol-half, b64 packed writes
        #pragma unroll
        for (int half = 0; half < 2; ++half) {
            __syncthreads();
            if ((w >> 1) == half) {            // waves whose nw == half*64
                #pragma unroll
                for (int i = 0; i < 4; ++i) {
                    const int sl = mw + i * 16 + quad * 4;
                    #pragma unroll
                    for (int j = 0; j < 4; ++j) {
                        const int dl = j * 16 + col;     // 0..63 within half
                        ushort4 ov;
                        ov.x = f2bf(acc[i][j][0]); ov.y = f2bf(acc[i][j][1]);
                        ov.z = f2bf(acc[i][j][2]); ov.w = f2bf(acc[i][j][3]);
                        *(ushort4*)&Es[dl * 136 + sl] = ov;
                    }
                }
            }
            __syncthreads();
            #pragma unroll
            for (int k = 0; k < 4; ++k) {
                const int c  = tid + k * 256;
                const int dl = c >> 4;               // 0..63 within half
                const int s8 = (c & 15) * 8;
                const int d  = half * 64 + dl;
                const bf16x8 v = *(const bf16x8*)&Es[dl * 136 + s8];
                *(bf16x8*)(Vb + ((size_t)(bb2 * H + hh0 + (d >> 6)) * Dh + (d & 63)) * S
                           + ssb + s8) = v;
            }
        }
    } else {
        // Q/K with fused RoPE from table; Es[row][d] per m-half
        unsigned short* dp = (wsel == 0) ? Qb : Kb;
        const float qscale = (wsel == 0) ? 0.125f : 1.0f;   // D^-0.5 for Q
        #pragma unroll
        for (int half = 0; half < 2; ++half) {
            __syncthreads();
            if ((w & 1) == half) {             // waves whose mw == half*64
                #pragma unroll
                for (int i = 0; i < 4; ++i) {
                    #pragma unroll
                    for (int r = 0; r < 4; ++r) {
                        const int rl = i * 16 + quad * 4 + r;   // 0..63 local
                        const int ss = ssb + half * 64 + rl;
                        const float2 t0 = ((const float2*)Tab)[(size_t)(bb2 * S + ss) * 32 + col];
                        const float2 t1 = ((const float2*)Tab)[(size_t)(bb2 * S + ss) * 32 + col + 16];
                        const float a0 = acc[i][0][r] * qscale, a1 = acc[i][1][r] * qscale;
                        const float a2 = acc[i][2][r] * qscale, a3 = acc[i][3][r] * qscale;
                        unsigned short* e = &Es[rl * 136 + nw];
                        e[col]      = f2bf(a0 * t0.x - a2 * t0.y);
                        e[col + 16] = f2bf(a1 * t1.x - a3 * t1.y);
                        e[col + 32] = f2bf(a2 * t0.x + a0 * t0.y);
                        e[col + 48] = f2bf(a3 * t1.x + a1 * t1.y);
                    }
                }
            }
            __syncthreads();
            #pragma unroll
            for (int k = 0; k < 4; ++k) {
                const int c  = tid + k * 256;
                const int rl = c >> 4;               // 0..63 local row
                const int d8 = (c & 15) * 8;
                const bf16x8 v = *(const bf16x8*)&Es[rl * 136 + d8];
                *(bf16x8*)(dp + ((size_t)(bb2 * H + hh0 + (d8 >> 6)) * S
                                 + ssb + half * 64 + rl) * Dh + (d8 & 63)) = v;
            }
        }
    }
}

// ---------------------------------------------------------------------------
// Kernel 2: flash attention — R4 body with T14 async-split load scheduling:
//   * mask loads for tile kt+1 issued RIGHT AFTER softmax consumes mv
//     (mv dead there; loads land directly in mv — mvp ping-pong + 32
//     movs/tile eliminated; issue->use window ~300 -> ~600 cyc).
//   * K/V loads for tile kt+2 issued RIGHT AFTER the drain consumes kp/vp
//     (window ~300 -> ~700 cyc). Prologue stages tile0, pre-issues tile1.
//   Rationale: R4 cut VALU 52->36% with zero time change => critical path is
//   exposed global-load latency at 2 waves/SIMD, not issue bandwidth.
//   grid = (S/128, B*H) = 512 blocks, 256 thr.
// ---------------------------------------------------------------------------
#define KSd 72
#define LOG2E  1.4426950408889634f
#define NEG8L (-11.541560327111707f)      // -8 * log2(e); exp(s-8) == exp2(fma)
#define NT (S / 64)

__global__ __launch_bounds__(256) void attn_kernel(const unsigned short* __restrict__ Q,
                                                   const unsigned short* __restrict__ K,
                                                   const unsigned short* __restrict__ V,
                                                   const float* __restrict__ mask,
                                                   float* __restrict__ out) {
    __shared__ __align__(16) unsigned short Ks[2][64 * KSd];   // [key][d]
    __shared__ __align__(16) unsigned short Vt[2][64 * KSd];   // [d][key]
    __shared__ __align__(16) unsigned short Ps[4 * 32 * KSd];

    const int tid  = threadIdx.x;
    const int w    = tid >> 6;
    const int lane = tid & 63;
    const int col  = lane & 15;
    const int quad = lane >> 4;
    const int bh   = blockIdx.y;
    const int b    = bh >> 4, h = bh & 15;
    const int q0   = blockIdx.x * 128;
    const int qw   = q0 + w * 32;             // wave's q base (32 rows)

    const int srow = tid >> 3;            // 0..31
    const int sc8  = (tid & 7) * 8;

    // Q fragments: qa[u][kc] — lane holds Q[q=qw+u*16+col][kc*32+quad*8 ..+7]
    bf16x8 qa[2][2];
    #pragma unroll
    for (int u = 0; u < 2; ++u) {
        const unsigned short* qrow = Q + ((size_t)bh * S + qw + u * 16 + col) * Dh;
        qa[u][0] = *(const bf16x8*)(qrow + quad * 8);
        qa[u][1] = *(const bf16x8*)(qrow + 32 + quad * 8);
    }

    f32x4 o[4][2] = {};                        // O^T frags: [d-frag g][q-frag u]
    float lsum[2] = {0.f, 0.f};
    const float* mbase = mask + (size_t)b * S * S;
    unsigned short* pw = Ps + w * 32 * KSd;
    const unsigned short* Kbase = K + (size_t)bh * S * Dh;
    const unsigned short* Vbase = V + (size_t)bh * Dh * S;   // transposed

    // ---- prologue: tile0 K/V + mask(tile0) into regs; stage tile0 to LDS
    //      buffer 0; then pre-issue tile1 K/V loads (drained at kt=0). ----
    bf16x8 kp[2], vp[2];
    float4 mv[4][2];
    #pragma unroll
    for (int cc = 0; cc < 2; ++cc) {
        kp[cc] = *(const bf16x8*)(Kbase + (size_t)(srow + cc * 32) * Dh + sc8);
        vp[cc] = *(const bf16x8*)(Vbase + (size_t)(srow + cc * 32) * S + sc8);
    }
    #pragma unroll
    for (int u = 0; u < 2; ++u)
        #pragma unroll
        for (int f = 0; f < 4; ++f)
            mv[f][u] = *(const float4*)(mbase + (size_t)(qw + u * 16 + col) * S
                                        + f * 16 + quad * 4);
    #pragma unroll
    for (int cc = 0; cc < 2; ++cc) {
        const int row = srow + cc * 32;
        *(bf16x8*)&Ks[0][row * KSd + sc8] = kp[cc];
        *(bf16x8*)&Vt[0][row * KSd + sc8] = vp[cc];
    }
    #pragma unroll
    for (int cc = 0; cc < 2; ++cc) {        // issue tile1 (no wait)
        kp[cc] = *(const bf16x8*)(Kbase + (size_t)(64 + srow + cc * 32) * Dh + sc8);
        vp[cc] = *(const bf16x8*)(Vbase + (size_t)(srow + cc * 32) * S + 64 + sc8);
    }
    __syncthreads();

    for (int kt = 0; kt < NT; ++kt) {
        const int cur = kt & 1;

        // ---- S^T = K · Q^T : C[m=key][n=q] ----
        f32x4 sc[4][2] = {};
        #pragma unroll
        for (int f = 0; f < 4; ++f) {
            const bf16x8 ka0 = *(const bf16x8*)&Ks[cur][(f * 16 + col) * KSd + quad * 8];
            const bf16x8 ka1 = *(const bf16x8*)&Ks[cur][(f * 16 + col) * KSd + 32 + quad * 8];
            #pragma unroll
            for (int u = 0; u < 2; ++u) {
                sc[f][u] = __builtin_amdgcn_mfma_f32_16x16x32_bf16(ka0, qa[u][0], sc[f][u], 0, 0, 0);
                sc[f][u] = __builtin_amdgcn_mfma_f32_16x16x32_bf16(ka1, qa[u][1], sc[f][u], 0, 0, 0);
            }
        }

        // ---- static-shift softmax numerator + packed P̃ store (consumes mv) ----
        #pragma unroll
        for (int u = 0; u < 2; ++u) {
            #pragma unroll
            for (int f = 0; f < 4; ++f) {
                sc[f][u][0] += mv[f][u].x; sc[f][u][1] += mv[f][u].y;
                sc[f][u][2] += mv[f][u].z; sc[f][u][3] += mv[f][u].w;
            }
            #pragma unroll
            for (int f = 0; f < 4; ++f)
                #pragma unroll
                for (int r = 0; r < 4; ++r) {
                    const float pv = __builtin_amdgcn_exp2f(
                        __builtin_fmaf(sc[f][u][r], LOG2E, NEG8L));
                    sc[f][u][r] = pv;
                    lsum[u] += pv;
                }
            unsigned short* pq = pw + (u * 16 + col) * KSd;
            #pragma unroll
            for (int f = 0; f < 4; ++f) {
                *(uint2*)&pq[f * 16 + quad * 4] =
                    make_uint2(cvt_pk_bf16(sc[f][u][0], sc[f][u][1]),
                               cvt_pk_bf16(sc[f][u][2], sc[f][u][3]));
            }
        }

        // ---- mv dead: issue mask loads for tile kt+1 directly into mv ----
        if (kt + 1 < NT) {
            #pragma unroll
            for (int u = 0; u < 2; ++u)
                #pragma unroll
                for (int f = 0; f < 4; ++f)
                    mv[f][u] = *(const float4*)(mbase + (size_t)(qw + u * 16 + col) * S
                                                + (kt + 1) * 64 + f * 16 + quad * 4);
        }

        // ---- drain K/V(kt+1) into LDS[nxt]; then issue K/V(kt+2) loads ----
        if (kt + 1 < NT) {
            const int nxt = cur ^ 1;
            #pragma unroll
            for (int cc = 0; cc < 2; ++cc) {
                const int row = srow + cc * 32;
                *(bf16x8*)&Ks[nxt][row * KSd + sc8] = kp[cc];
                *(bf16x8*)&Vt[nxt][row * KSd + sc8] = vp[cc];
            }
            if (kt + 2 < NT) {
                #pragma unroll
                for (int cc = 0; cc < 2; ++cc) {
                    kp[cc] = *(const bf16x8*)(Kbase + (size_t)((kt + 2) * 64 + srow + cc * 32) * Dh + sc8);
                    vp[cc] = *(const bf16x8*)(Vbase + (size_t)(srow + cc * 32) * S + (kt + 2) * 64 + sc8);
                }
            }
        }
        __threadfence_block();   // wave-private Ps visible before PV reads

        // ---- O^T += V^T · P̃ ----
        #pragma unroll
        for (int kc = 0; kc < 2; ++kc) {
            bf16x8 pb[2];
            #pragma unroll
            for (int u = 0; u < 2; ++u)
                pb[u] = *(const bf16x8*)&pw[(u * 16 + col) * KSd + kc * 32 + quad * 8];
            #pragma unroll
            for (int g = 0; g < 4; ++g) {
                const bf16x8 va = *(const bf16x8*)&Vt[cur][(g * 16 + col) * KSd + kc * 32 + quad * 8];
                #pragma unroll
                for (int u = 0; u < 2; ++u)
                    o[g][u] = __builtin_amdgcn_mfma_f32_16x16x32_bf16(va, pb[u], o[g][u], 0, 0, 0);
            }
        }
        __syncthreads();   // single barrier: iter kt writes->nxt, reads->cur
    }

    // ---- deferred l reduction (quads hold disjoint key subsets) ----
    #pragma unroll
    for (int u = 0; u < 2; ++u) {
        lsum[u] += __shfl_xor(lsum[u], 16, 64);
        lsum[u] += __shfl_xor(lsum[u], 32, 64);
    }

    // ---- epilogue: lane (quad,r,col) holds O[q=qw+u*16+col][d=g*16+quad*4+r]
    #pragma unroll
    for (int u = 0; u < 2; ++u) {
        const float inv = 1.f / lsum[u];
        float* op = out + ((size_t)b * S + qw + u * 16 + col) * DM + h * Dh + quad * 4;
        #pragma unroll
        for (int g = 0; g < 4; ++g) {
            float4 ov;
            ov.x = o[g][u][0] * inv; ov.y = o[g][u][1] * inv;
            ov.z = o[g][u][2] * inv; ov.w = o[g][u][3] * inv;
            *(float4*)(op + g * 16) = ov;
        }
    }
}

// ---------------------------------------------------------------------------
extern "C" void kernel_launch(void* const* d_in, const int* in_sizes, int n_in,
                              void* d_out, int out_size, void* d_ws, size_t ws_size,
                              hipStream_t stream) {
    const float* hs   = (const float*)d_in[0];  // (B,S,DM)
    const float* mask = (const float*)d_in[1];  // (B,1,S,S)
    const int*   pos  = (const int*)  d_in[2];  // (B,S)
    const float* Wq   = (const float*)d_in[3];
    const float* Wk   = (const float*)d_in[4];
    const float* Wv   = (const float*)d_in[5];
    float* out = (float*)d_out;

    // workspace (ushort units): Xb 4,194,304 | Wb 3,145,728 |
    //   Qb,Kb [B,H,S,Dh], Vb [B,H,Dh,S] each 4,194,304 | Tab 1 MB (float2)
    unsigned short* Xb = (unsigned short*)d_ws;
    unsigned short* Wb = Xb + 4194304;
    unsigned short* Qb = Wb + 3145728;
    unsigned short* Kb = Qb + 4194304;
    unsigned short* Vb = Kb + 4194304;
    float*          Tab = (float*)(Vb + 4194304);   // 262144 floats

    cast_kernel<<<7168, 256, 0, stream>>>(hs, Wq, Wk, Wv, Xb, Wb);
    rope_tab_kernel<<<512, 256, 0, stream>>>(pos, Tab);
    qkv_gemm<<<dim3(32, 24), 256, 0, stream>>>(Xb, Wb, Tab, Qb, Kb, Vb);
    attn_kernel<<<dim3(S / 128, BH), 256, 0, stream>>>(Qb, Kb, Vb, mask, out);
}

// Round 7
// 219.483 us; speedup vs baseline: 1.1174x; 1.0137x over previous
//
#include <hip/hip_runtime.h>
#include <math.h>

// Problem constants (from reference)
#define B  2
#define S  2048
#define DM 1024
#define H  16
#define Dh 64
#define BH (B*H)

typedef short  bf16x8 __attribute__((ext_vector_type(8)));
typedef float  f32x4  __attribute__((ext_vector_type(4)));

__device__ __forceinline__ unsigned short f2bf(float f) {
    unsigned u = __float_as_uint(f);
    u = (u + 0x7fffu + ((u >> 16) & 1u)) >> 16;   // RNE, no NaN inputs here
    return (unsigned short)u;
}

// gfx950 packed f32->bf16 (RNE) — one VALU op for two converts+pack.
__device__ __forceinline__ unsigned cvt_pk_bf16(float lo, float hi) {
    unsigned r;
    asm("v_cvt_pk_bf16_f32 %0, %1, %2" : "=v"(r) : "v"(lo), "v"(hi));
    return r;
}

// Barrier that waits ONLY on LDS ops (lgkmcnt), leaving global-load register
// prefetch in flight across the barrier (counted-vmcnt discipline).
// CRITICAL (R6 failure): s_barrier is IntrNoMem — without a compiler memory
// fence on BOTH sides, LDS reads after the barrier hoist between the waitcnt
// and the barrier (reading other waves' rows before they are written).
// The trailing empty asm is a zero-instruction compiler fence.
__device__ __forceinline__ void lds_barrier() {
    asm volatile("s_waitcnt lgkmcnt(0)" ::: "memory");
    __builtin_amdgcn_s_barrier();
    asm volatile("" ::: "memory");
}

// ---------------------------------------------------------------------------
// Kernel 0a: cast hidden_states + Wq|Wk|Wv (fp32) to bf16 workspace buffers.
// ---------------------------------------------------------------------------
__global__ __launch_bounds__(256) void cast_kernel(const float* __restrict__ X,
                                                   const float* __restrict__ Wq,
                                                   const float* __restrict__ Wk,
                                                   const float* __restrict__ Wv,
                                                   unsigned short* __restrict__ Xb,
                                                   unsigned short* __restrict__ Wb) {
    const long c = (long)(blockIdx.x * 256 + threadIdx.x) * 4;
    const float* src;
    unsigned short* dst;
    if (c < 4194304L) {
        src = X + c;  dst = Xb + c;
    } else {
        const long c2 = c - 4194304L;
        const int  wi = (int)(c2 >> 20);
        const long r  = c2 & 1048575L;
        src = (wi == 0 ? Wq : (wi == 1 ? Wk : Wv)) + r;
        dst = Wb + c2;
    }
    const float4 v = *(const float4*)src;
    ushort4 o;
    o.x = f2bf(v.x); o.y = f2bf(v.y); o.z = f2bf(v.z); o.w = f2bf(v.w);
    *(ushort4*)dst = o;
}

// ---------------------------------------------------------------------------
// Kernel 0b: RoPE cos/sin table: Tab[(b*S+s)*32 + i] = (cos, sin) of
//   pos[b,s] * 10000^(-i/32).  1 MB, L2-resident.
// ---------------------------------------------------------------------------
__global__ __launch_bounds__(256) void rope_tab_kernel(const int* __restrict__ pos,
                                                       float* __restrict__ Tab) {
    const int idx = blockIdx.x * 256 + threadIdx.x;   // < B*S*32 = 131072
    const int i  = idx & 31;
    const int bs = idx >> 5;
    const float p   = (float)pos[bs];
    const float inv = exp2f(-(float)i * 0.41524101186092029f);  // log2(1e4)/32
    float sn, cs;
    sincosf(p * inv, &sn, &cs);
    ((float2*)Tab)[idx] = make_float2(cs, sn);
}

// async global->LDS, 16B per lane
__device__ __forceinline__ void gload_lds16(const unsigned short* g, unsigned short* l) {
    __builtin_amdgcn_global_load_lds(
        (const __attribute__((address_space(1))) unsigned int*)g,
        (__attribute__((address_space(3))) unsigned int*)l,
        16, 0, 0);
}

// ---------------------------------------------------------------------------
// Kernel 1: fused QKV GEMM (R0 verified config: BK=32, 16 MFMA/barrier —
//   BK=64 regressed −19 µs in R3). global_load_lds staging with XOR chunk
//   swizzle. Epilogue: RoPE via table + LDS round-trip (Es, 2 halves) so ALL
//   global stores are coalesced 16B. V written transposed [B,H,Dh,S].
//   NOTE: its __syncthreads after staging MUST drain vmcnt (global_load_lds
//   writes LDS directly) — unchanged.
// ---------------------------------------------------------------------------
__global__ __launch_bounds__(256) void qkv_gemm(const unsigned short* __restrict__ Xb,
                                                const unsigned short* __restrict__ Wb,
                                                const float* __restrict__ Tab,
                                                unsigned short* __restrict__ Qb,
                                                unsigned short* __restrict__ Kb,
                                                unsigned short* __restrict__ Vb) {
    __shared__ __align__(16) unsigned short As[128 * 32];
    __shared__ __align__(16) unsigned short Bs[128 * 32];
    __shared__ __align__(16) unsigned short Es[64 * 136];   // epilogue staging

    const int tid  = threadIdx.x;
    const int w    = tid >> 6;
    const int lane = tid & 63;
    const int col  = lane & 15;
    const int quad = lane >> 4;
    const int m0 = blockIdx.x * 128;
    const int n0 = blockIdx.y * 128;
    const int mw = (w & 1) * 64;
    const int nw = (w >> 1) * 64;

    // staging: lane i loads row i>>2, global chunk (i&3)^(row&3)  (XOR swizzle)
    const int srow = lane >> 2;
    const int sk8  = (((lane & 3) ^ (srow & 3))) * 8;

    f32x4 acc[4][4] = {};

    for (int k0 = 0; k0 < 1024; k0 += 32) {
        __syncthreads();
        #pragma unroll
        for (int it = 0; it < 2; ++it) {
            const int rbase = w * 16 + it * 64;
            gload_lds16(Xb + (size_t)(m0 + rbase + srow) * 1024 + k0 + sk8,
                        &As[rbase * 32]);
            gload_lds16(Wb + (size_t)(n0 + rbase + srow) * 1024 + k0 + sk8,
                        &Bs[rbase * 32]);
        }
        __syncthreads();

        // global k-chunk quad lives at LDS slot quad^(row&3); row&3 == col&3
        const int fs = (quad ^ (col & 3)) * 8;
        bf16x8 a[4], bb[4];
        #pragma unroll
        for (int i = 0; i < 4; ++i)
            a[i] = *(const bf16x8*)&As[(mw + i * 16 + col) * 32 + fs];
        #pragma unroll
        for (int j = 0; j < 4; ++j)
            bb[j] = *(const bf16x8*)&Bs[(nw + j * 16 + col) * 32 + fs];
        #pragma unroll
        for (int i = 0; i < 4; ++i)
            #pragma unroll
            for (int j = 0; j < 4; ++j)
                acc[i][j] = __builtin_amdgcn_mfma_f32_16x16x32_bf16(a[i], bb[j], acc[i][j], 0, 0, 0);
    }

    // ---- epilogue ----
    const int wsel = n0 >> 10;                 // 0=Q, 1=K, 2=V
    const int hh0  = (n0 & 1023) >> 6;         // base head of this n-tile
    const int bb2  = m0 >> 11;                 // batch (block never straddles)
    const int ssb  = m0 & 2047;                // seq base

    if (wsel == 2) {
        // V -> [B,H,Dh,S]; Es[dl][ssl] per dcol-half, b64 packed writes
        #pragma unroll
        for (int half = 0; half < 2; ++half) {
            __syncthreads();
            if ((w >> 1) == half) {            // waves whose nw == half*64
                #pragma unroll
                for (int i = 0; i < 4; ++i) {
                    const int sl = mw + i * 16 + quad * 4;
                    #pragma unroll
                    for (int j = 0; j < 4; ++j) {
                        const int dl = j * 16 + col;     // 0..63 within half
                        ushort4 ov;
                        ov.x = f2bf(acc[i][j][0]); ov.y = f2bf(acc[i][j][1]);
                        ov.z = f2bf(acc[i][j][2]); ov.w = f2bf(acc[i][j][3]);
                        *(ushort4*)&Es[dl * 136 + sl] = ov;
                    }
                }
            }
            __syncthreads();
            #pragma unroll
            for (int k = 0; k < 4; ++k) {
                const int c  = tid + k * 256;
                const int dl = c >> 4;               // 0..63 within half
                const int s8 = (c & 15) * 8;
                const int d  = half * 64 + dl;
                const bf16x8 v = *(const bf16x8*)&Es[dl * 136 + s8];
                *(bf16x8*)(Vb + ((size_t)(bb2 * H + hh0 + (d >> 6)) * Dh + (d & 63)) * S
                           + ssb + s8) = v;
            }
        }
    } else {
        // Q/K with fused RoPE from table; Es[row][d] per m-half
        unsigned short* dp = (wsel == 0) ? Qb : Kb;
        const float qscale = (wsel == 0) ? 0.125f : 1.0f;   // D^-0.5 for Q
        #pragma unroll
        for (int half = 0; half < 2; ++half) {
            __syncthreads();
            if ((w & 1) == half) {             // waves whose mw == half*64
                #pragma unroll
                for (int i = 0; i < 4; ++i) {
                    #pragma unroll
                    for (int r = 0; r < 4; ++r) {
                        const int rl = i * 16 + quad * 4 + r;   // 0..63 local
                        const int ss = ssb + half * 64 + rl;
                        const float2 t0 = ((const float2*)Tab)[(size_t)(bb2 * S + ss) * 32 + col];
                        const float2 t1 = ((const float2*)Tab)[(size_t)(bb2 * S + ss) * 32 + col + 16];
                        const float a0 = acc[i][0][r] * qscale, a1 = acc[i][1][r] * qscale;
                        const float a2 = acc[i][2][r] * qscale, a3 = acc[i][3][r] * qscale;
                        unsigned short* e = &Es[rl * 136 + nw];
                        e[col]      = f2bf(a0 * t0.x - a2 * t0.y);
                        e[col + 16] = f2bf(a1 * t1.x - a3 * t1.y);
                        e[col + 32] = f2bf(a2 * t0.x + a0 * t0.y);
                        e[col + 48] = f2bf(a3 * t1.x + a1 * t1.y);
                    }
                }
            }
            __syncthreads();
            #pragma unroll
            for (int k = 0; k < 4; ++k) {
                const int c  = tid + k * 256;
                const int rl = c >> 4;               // 0..63 local row
                const int d8 = (c & 15) * 8;
                const bf16x8 v = *(const bf16x8*)&Es[rl * 136 + d8];
                *(bf16x8*)(dp + ((size_t)(bb2 * H + hh0 + (d8 >> 6)) * S
                                 + ssb + half * 64 + rl) * Dh + (d8 & 63)) = v;
            }
        }
    }
}

// ---------------------------------------------------------------------------
// Kernel 2: flash attention — R6 structure with the barrier race FIXED
//   (two-sided compiler fence around raw s_barrier; see lds_barrier()).
//   Counted-wait barriers: tile-boundary sync waits lgkmcnt only; the
//   mask(kt+1) and K/V(kt+2) register prefetches stay in flight across the
//   barrier and complete via compiler-counted vmcnt at their use sites.
//   grid = (S/128, B*H) = 512 blocks, 256 thr.
// ---------------------------------------------------------------------------
#define KSd 72
#define LOG2E  1.4426950408889634f
#define NEG8L (-11.541560327111707f)      // -8 * log2(e); exp(s-8) == exp2(fma)
#define NT (S / 64)

__global__ __launch_bounds__(256) void attn_kernel(const unsigned short* __restrict__ Q,
                                                   const unsigned short* __restrict__ K,
                                                   const unsigned short* __restrict__ V,
                                                   const float* __restrict__ mask,
                                                   float* __restrict__ out) {
    __shared__ __align__(16) unsigned short Ks[2][64 * KSd];   // [key][d]
    __shared__ __align__(16) unsigned short Vt[2][64 * KSd];   // [d][key]
    __shared__ __align__(16) unsigned short Ps[4 * 32 * KSd];

    const int tid  = threadIdx.x;
    const int w    = tid >> 6;
    const int lane = tid & 63;
    const int col  = lane & 15;
    const int quad = lane >> 4;
    const int bh   = blockIdx.y;
    const int b    = bh >> 4, h = bh & 15;
    const int q0   = blockIdx.x * 128;
    const int qw   = q0 + w * 32;             // wave's q base (32 rows)

    const int srow = tid >> 3;            // 0..31
    const int sc8  = (tid & 7) * 8;

    // Q fragments: qa[u][kc] — lane holds Q[q=qw+u*16+col][kc*32+quad*8 ..+7]
    bf16x8 qa[2][2];
    #pragma unroll
    for (int u = 0; u < 2; ++u) {
        const unsigned short* qrow = Q + ((size_t)bh * S + qw + u * 16 + col) * Dh;
        qa[u][0] = *(const bf16x8*)(qrow + quad * 8);
        qa[u][1] = *(const bf16x8*)(qrow + 32 + quad * 8);
    }

    f32x4 o[4][2] = {};                        // O^T frags: [d-frag g][q-frag u]
    float lsum[2] = {0.f, 0.f};
    const float* mbase = mask + (size_t)b * S * S;
    unsigned short* pw = Ps + w * 32 * KSd;
    const unsigned short* Kbase = K + (size_t)bh * S * Dh;
    const unsigned short* Vbase = V + (size_t)bh * Dh * S;   // transposed

    // ---- prologue: tile0 K/V + mask(tile0) into regs; stage tile0 to LDS
    //      buffer 0; then pre-issue tile1 K/V loads (drained at kt=0). ----
    bf16x8 kp[2], vp[2];
    float4 mv[4][2];
    #pragma unroll
    for (int cc = 0; cc < 2; ++cc) {
        kp[cc] = *(const bf16x8*)(Kbase + (size_t)(srow + cc * 32) * Dh + sc8);
        vp[cc] = *(const bf16x8*)(Vbase + (size_t)(srow + cc * 32) * S + sc8);
    }
    #pragma unroll
    for (int u = 0; u < 2; ++u)
        #pragma unroll
        for (int f = 0; f < 4; ++f)
            mv[f][u] = *(const float4*)(mbase + (size_t)(qw + u * 16 + col) * S
                                        + f * 16 + quad * 4);
    #pragma unroll
    for (int cc = 0; cc < 2; ++cc) {
        const int row = srow + cc * 32;
        *(bf16x8*)&Ks[0][row * KSd + sc8] = kp[cc];
        *(bf16x8*)&Vt[0][row * KSd + sc8] = vp[cc];
    }
    #pragma unroll
    for (int cc = 0; cc < 2; ++cc) {        // issue tile1 (stays in flight)
        kp[cc] = *(const bf16x8*)(Kbase + (size_t)(64 + srow + cc * 32) * Dh + sc8);
        vp[cc] = *(const bf16x8*)(Vbase + (size_t)(srow + cc * 32) * S + 64 + sc8);
    }
    lds_barrier();

    for (int kt = 0; kt < NT; ++kt) {
        const int cur = kt & 1;

        // ---- S^T = K · Q^T : C[m=key][n=q] ----
        f32x4 sc[4][2] = {};
        #pragma unroll
        for (int f = 0; f < 4; ++f) {
            const bf16x8 ka0 = *(const bf16x8*)&Ks[cur][(f * 16 + col) * KSd + quad * 8];
            const bf16x8 ka1 = *(const bf16x8*)&Ks[cur][(f * 16 + col) * KSd + 32 + quad * 8];
            #pragma unroll
            for (int u = 0; u < 2; ++u) {
                sc[f][u] = __builtin_amdgcn_mfma_f32_16x16x32_bf16(ka0, qa[u][0], sc[f][u], 0, 0, 0);
                sc[f][u] = __builtin_amdgcn_mfma_f32_16x16x32_bf16(ka1, qa[u][1], sc[f][u], 0, 0, 0);
            }
        }

        // ---- static-shift softmax numerator + packed P̃ store (consumes mv) ----
        #pragma unroll
        for (int u = 0; u < 2; ++u) {
            #pragma unroll
            for (int f = 0; f < 4; ++f) {
                sc[f][u][0] += mv[f][u].x; sc[f][u][1] += mv[f][u].y;
                sc[f][u][2] += mv[f][u].z; sc[f][u][3] += mv[f][u].w;
            }
            #pragma unroll
            for (int f = 0; f < 4; ++f)
                #pragma unroll
                for (int r = 0; r < 4; ++r) {
                    const float pv = __builtin_amdgcn_exp2f(
                        __builtin_fmaf(sc[f][u][r], LOG2E, NEG8L));
                    sc[f][u][r] = pv;
                    lsum[u] += pv;
                }
            unsigned short* pq = pw + (u * 16 + col) * KSd;
            #pragma unroll
            for (int f = 0; f < 4; ++f) {
                *(uint2*)&pq[f * 16 + quad * 4] =
                    make_uint2(cvt_pk_bf16(sc[f][u][0], sc[f][u][1]),
                               cvt_pk_bf16(sc[f][u][2], sc[f][u][3]));
            }
        }

        // ---- mv dead: issue mask loads for tile kt+1 directly into mv ----
        if (kt + 1 < NT) {
            #pragma unroll
            for (int u = 0; u < 2; ++u)
                #pragma unroll
                for (int f = 0; f < 4; ++f)
                    mv[f][u] = *(const float4*)(mbase + (size_t)(qw + u * 16 + col) * S
                                                + (kt + 1) * 64 + f * 16 + quad * 4);
        }

        // ---- drain K/V(kt+1) into LDS[nxt]; then issue K/V(kt+2) loads ----
        if (kt + 1 < NT) {
            const int nxt = cur ^ 1;
            #pragma unroll
            for (int cc = 0; cc < 2; ++cc) {
                const int row = srow + cc * 32;
                *(bf16x8*)&Ks[nxt][row * KSd + sc8] = kp[cc];
                *(bf16x8*)&Vt[nxt][row * KSd + sc8] = vp[cc];
            }
            if (kt + 2 < NT) {
                #pragma unroll
                for (int cc = 0; cc < 2; ++cc) {
                    kp[cc] = *(const bf16x8*)(Kbase + (size_t)((kt + 2) * 64 + srow + cc * 32) * Dh + sc8);
                    vp[cc] = *(const bf16x8*)(Vbase + (size_t)(srow + cc * 32) * S + (kt + 2) * 64 + sc8);
                }
            }
        }

        // wave-private Ps write->read ordering (same-wave): LDS wait + fences.
        asm volatile("s_waitcnt lgkmcnt(0)" ::: "memory");
        __builtin_amdgcn_sched_barrier(0);

        // ---- O^T += V^T · P̃ ----
        #pragma unroll
        for (int kc = 0; kc < 2; ++kc) {
            bf16x8 pb[2];
            #pragma unroll
            for (int u = 0; u < 2; ++u)
                pb[u] = *(const bf16x8*)&pw[(u * 16 + col) * KSd + kc * 32 + quad * 8];
            #pragma unroll
            for (int g = 0; g < 4; ++g) {
                const bf16x8 va = *(const bf16x8*)&Vt[cur][(g * 16 + col) * KSd + kc * 32 + quad * 8];
                #pragma unroll
                for (int u = 0; u < 2; ++u)
                    o[g][u] = __builtin_amdgcn_mfma_f32_16x16x32_bf16(va, pb[u], o[g][u], 0, 0, 0);
            }
        }
        // tile-boundary barrier: LDS-only wait; mask/KV prefetch stays in
        // flight (they complete via compiler-counted vmcnt at use sites).
        lds_barrier();
    }

    // ---- deferred l reduction (quads hold disjoint key subsets) ----
    #pragma unroll
    for (int u = 0; u < 2; ++u) {
        lsum[u] += __shfl_xor(lsum[u], 16, 64);
        lsum[u] += __shfl_xor(lsum[u], 32, 64);
    }

    // ---- epilogue: lane (quad,r,col) holds O[q=qw+u*16+col][d=g*16+quad*4+r]
    #pragma unroll
    for (int u = 0; u < 2; ++u) {
        const float inv = 1.f / lsum[u];
        float* op = out + ((size_t)b * S + qw + u * 16 + col) * DM + h * Dh + quad * 4;
        #pragma unroll
        for (int g = 0; g < 4; ++g) {
            float4 ov;
            ov.x = o[g][u][0] * inv; ov.y = o[g][u][1] * inv;
            ov.z = o[g][u][2] * inv; ov.w = o[g][u][3] * inv;
            *(float4*)(op + g * 16) = ov;
        }
    }
}

// ---------------------------------------------------------------------------
extern "C" void kernel_launch(void* const* d_in, const int* in_sizes, int n_in,
                              void* d_out, int out_size, void* d_ws, size_t ws_size,
                              hipStream_t stream) {
    const float* hs   = (const float*)d_in[0];  // (B,S,DM)
    const float* mask = (const float*)d_in[1];  // (B,1,S,S)
    const int*   pos  = (const int*)  d_in[2];  // (B,S)
    const float* Wq   = (const float*)d_in[3];
    const float* Wk   = (const float*)d_in[4];
    const float* Wv   = (const float*)d_in[5];
    float* out = (float*)d_out;

    // workspace (ushort units): Xb 4,194,304 | Wb 3,145,728 |
    //   Qb,Kb [B,H,S,Dh], Vb [B,H,Dh,S] each 4,194,304 | Tab 1 MB (float2)
    unsigned short* Xb = (unsigned short*)d_ws;
    unsigned short* Wb = Xb + 4194304;
    unsigned short* Qb = Wb + 3145728;
    unsigned short* Kb = Qb + 4194304;
    unsigned short* Vb = Kb + 4194304;
    float*          Tab = (float*)(Vb + 4194304);   // 262144 floats

    cast_kernel<<<7168, 256, 0, stream>>>(hs, Wq, Wk, Wv, Xb, Wb);
    rope_tab_kernel<<<512, 256, 0, stream>>>(pos, Tab);
    qkv_gemm<<<dim3(32, 24), 256, 0, stream>>>(Xb, Wb, Tab, Qb, Kb, Vb);
    attn_kernel<<<dim3(S / 128, BH), 256, 0, stream>>>(Qb, Kb, Vb, mask, out);
}